// Round 5
// baseline (53.138 us; speedup 1.0000x reference)
//
#include <hip/hip_runtime.h>

#define BB 1024
#define LL 200
#define HH 512
#define NOUT 5
#define NSUB 4
#define BN_EPS 1e-5f

typedef __attribute__((ext_vector_type(8))) short bf16x8;
typedef __attribute__((ext_vector_type(4))) float f32x4;

static __device__ __forceinline__ unsigned short f2bf(float f) {
    unsigned u = __builtin_bit_cast(unsigned, f);
    unsigned r = (u + 0x7FFF + ((u >> 16) & 1)) >> 16;  // RNE
    return (unsigned short)r;
}

// ---------------- K1: pooled partial sums, 4 token-subsets/example -----
// Block bid = b*4 + s handles tokens t ≡ {2s, 2s+1} (mod 8) of example b.
// Predicated ALWAYS-8-wide gather: every chunk issues 8 loads (dummies hit
// the thread's first token row, L2-hot, masked by 0/1 multiply) so MLP
// stays deep for all lengths.
__global__ __launch_bounds__(256) void pool_partial(const int* __restrict__ tokens,
                                                    const int* __restrict__ lengths,
                                                    const float* __restrict__ emb,
                                                    float* __restrict__ part) {
    __shared__ int toks[LL];
    __shared__ float red[128][4];
    const int bid = blockIdx.x;
    const int b = bid >> 2;
    const int s = bid & 3;
    const int tid = threadIdx.x;
    const int len = lengths[b];
    for (int t = tid; t < len; t += 256) toks[t] = tokens[b * LL + t];
    __syncthreads();
    const int g = tid >> 7;
    const int q = tid & 127;
    const int c = q * 4;
    float ax = 0.f, ay = 0.f, az = 0.f, aw = 0.f;
    const int off = s * 2 + g;
    for (int t = off; t < len; t += 64) {
#pragma unroll
        for (int u = 0; u < 8; ++u) {
            const int tt = t + 8 * u;
            const int safe = tt < len ? tt : off;
            const float m = tt < len ? 1.f : 0.f;
            const float4 v = *(const float4*)&emb[(size_t)toks[safe] * HH + c];
            ax += m * v.x; ay += m * v.y; az += m * v.z; aw += m * v.w;
        }
    }
    if (g == 1) {
        red[q][0] = ax; red[q][1] = ay; red[q][2] = az; red[q][3] = aw;
    }
    __syncthreads();
    if (g == 0) {
        float4 o;
        o.x = ax + red[q][0];
        o.y = ay + red[q][1];
        o.z = az + red[q][2];
        o.w = aw + red[q][3];
        *(float4*)&part[(size_t)bid * HH + c] = o;
    }
}

// ---------------- K2: reduce partials -> Apk pack; W1 -> Bpk; zero ps --
__global__ __launch_bounds__(256) void pack_kernel(const float* __restrict__ part,
                                                   const int* __restrict__ lengths,
                                                   const float* __restrict__ W1,
                                                   unsigned short* __restrict__ Apk,
                                                   unsigned short* __restrict__ Bpk,
                                                   float* __restrict__ ps) {
    const int bid = blockIdx.x;
    const int tid = threadIdx.x;
    if (bid < 512) {
        const int idx = bid * 256 + tid;  // 131072 = 1024 examples * 128 quads
        const int b = idx >> 7;
        const int q = idx & 127;
        const int c = q * 4;
        float4 a = *(const float4*)&part[((size_t)(b * 4 + 0)) * HH + c];
        const float4 p1 = *(const float4*)&part[((size_t)(b * 4 + 1)) * HH + c];
        const float4 p2 = *(const float4*)&part[((size_t)(b * 4 + 2)) * HH + c];
        const float4 p3 = *(const float4*)&part[((size_t)(b * 4 + 3)) * HH + c];
        a.x += p1.x + p2.x + p3.x;
        a.y += p1.y + p2.y + p3.y;
        a.z += p1.z + p2.z + p3.z;
        a.w += p1.w + p2.w + p3.w;
        const float inv = 1.f / (float)lengths[b];
        const int lane = ((c >> 3) & 3) * 16 + (b & 15);
        const size_t eidx = (((size_t)(b >> 4) * 16 + (c >> 5)) * 64 + lane) * 8 + (c & 7);
        ushort4 o;
        o.x = f2bf(a.x * inv); o.y = f2bf(a.y * inv);
        o.z = f2bf(a.z * inv); o.w = f2bf(a.w * inv);
        *(ushort4*)&Apk[eidx] = o;
    } else {
        const int id = (bid - 512) * 256 + tid;  // 65536 threads, 4 elems each
        const int base = id * 4;
        const int k = base >> 9;
        const int n = base & 511;
        const float4 w = *(const float4*)&W1[(size_t)k * HH + n];
        const float wv[4] = {w.x, w.y, w.z, w.w};
#pragma unroll
        for (int i = 0; i < 4; ++i) {
            const int ni = n + i;
            const int lane = ((k >> 3) & 3) * 16 + (ni & 15);
            const size_t eidx = (((size_t)(ni >> 4) * 16 + (k >> 5)) * 64 + lane) * 8 + (k & 7);
            Bpk[eidx] = f2bf(wv[i]);
        }
        if (bid == 512) {  // zero ps+pq (1024 contiguous floats)
            ((float4*)ps)[tid] = make_float4(0.f, 0.f, 0.f, 0.f);
        }
    }
}

// ---------------- K3: h = A@W1 + b1 via MFMA, fused column stats -------
__global__ __launch_bounds__(256) void gemm1_mfma(const unsigned short* __restrict__ Apk,
                                                  const unsigned short* __restrict__ Bpk,
                                                  const float* __restrict__ b1,
                                                  float* __restrict__ hpre,
                                                  float* __restrict__ ps,
                                                  float* __restrict__ pq) {
    const int tid = threadIdx.x;
    const int lane = tid & 63;
    const int w = tid >> 6;
    const int mt0 = blockIdx.y * 4 + (w >> 1) * 2;
    const int nt0 = blockIdx.x * 4 + (w & 1) * 2;

    f32x4 acc[2][2];
#pragma unroll
    for (int i = 0; i < 2; ++i)
#pragma unroll
        for (int j = 0; j < 2; ++j) acc[i][j] = (f32x4){0.f, 0.f, 0.f, 0.f};

    const unsigned short* a0p = Apk + ((size_t)(mt0 + 0) * 16 * 64 + lane) * 8;
    const unsigned short* a1p = Apk + ((size_t)(mt0 + 1) * 16 * 64 + lane) * 8;
    const unsigned short* b0p = Bpk + ((size_t)(nt0 + 0) * 16 * 64 + lane) * 8;
    const unsigned short* b1p = Bpk + ((size_t)(nt0 + 1) * 16 * 64 + lane) * 8;
#pragma unroll 4
    for (int ks = 0; ks < 16; ++ks) {
        const bf16x8 a0 = *(const bf16x8*)(a0p + (size_t)ks * 512);
        const bf16x8 a1 = *(const bf16x8*)(a1p + (size_t)ks * 512);
        const bf16x8 bb0 = *(const bf16x8*)(b0p + (size_t)ks * 512);
        const bf16x8 bb1 = *(const bf16x8*)(b1p + (size_t)ks * 512);
        acc[0][0] = __builtin_amdgcn_mfma_f32_16x16x32_bf16(a0, bb0, acc[0][0], 0, 0, 0);
        acc[0][1] = __builtin_amdgcn_mfma_f32_16x16x32_bf16(a0, bb1, acc[0][1], 0, 0, 0);
        acc[1][0] = __builtin_amdgcn_mfma_f32_16x16x32_bf16(a1, bb0, acc[1][0], 0, 0, 0);
        acc[1][1] = __builtin_amdgcn_mfma_f32_16x16x32_bf16(a1, bb1, acc[1][1], 0, 0, 0);
    }

    const int col0 = nt0 * 16 + (lane & 15);
    const int col1 = col0 + 16;
    const float bias0 = b1[col0];
    const float bias1 = b1[col1];
    const int rbase = (lane >> 4) * 4;
    float s0 = 0.f, q0 = 0.f, s1 = 0.f, q1 = 0.f;
#pragma unroll
    for (int mi = 0; mi < 2; ++mi) {
        const int rowb = (mt0 + mi) * 16 + rbase;
#pragma unroll
        for (int r = 0; r < 4; ++r) {
            const float v0 = acc[mi][0][r] + bias0;
            const float v1 = acc[mi][1][r] + bias1;
            hpre[(size_t)(rowb + r) * HH + col0] = v0;
            hpre[(size_t)(rowb + r) * HH + col1] = v1;
            s0 += v0; q0 += v0 * v0;
            s1 += v1; q1 += v1 * v1;
        }
    }
    s0 += __shfl_xor(s0, 16, 64); s0 += __shfl_xor(s0, 32, 64);
    q0 += __shfl_xor(q0, 16, 64); q0 += __shfl_xor(q0, 32, 64);
    s1 += __shfl_xor(s1, 16, 64); s1 += __shfl_xor(s1, 32, 64);
    q1 += __shfl_xor(q1, 16, 64); q1 += __shfl_xor(q1, 32, 64);
    if (lane < 16) {
        atomicAdd(&ps[col0], s0);
        atomicAdd(&pq[col0], q0);
        atomicAdd(&ps[col1], s1);
        atomicAdd(&pq[col1], q1);
    }
}

// ---------------- K4: BN finalize + ReLU + GEMM2 -----------------------
__global__ __launch_bounds__(256) void bn_out_kernel(const float* __restrict__ Hm,
                                                     const float* __restrict__ ps,
                                                     const float* __restrict__ pq,
                                                     const float* __restrict__ gamma,
                                                     const float* __restrict__ beta,
                                                     const float* __restrict__ W2,
                                                     const float* __restrict__ b2,
                                                     float* __restrict__ out) {
    __shared__ float sscale[HH];
    __shared__ float sshift[HH];
    const int tid = threadIdx.x;
#pragma unroll
    for (int i = 0; i < 2; ++i) {
        const int j = tid + i * 256;
        const float mu = ps[j] * (1.f / (float)BB);
        const float var = pq[j] * (1.f / (float)BB) - mu * mu;
        const float sc = gamma[j] * rsqrtf(var + BN_EPS);
        sscale[j] = sc;
        sshift[j] = beta[j] - mu * sc;
    }
    __syncthreads();
    const int lane = tid & 63;
    const int wave = tid >> 6;
    const int row = blockIdx.x * 4 + wave;
    float w[8][NOUT];
#pragma unroll
    for (int j = 0; j < 8; ++j) {
        const int h = lane + j * 64;
#pragma unroll
        for (int k = 0; k < NOUT; ++k) w[j][k] = W2[h * NOUT + k];
    }
    float a0 = 0.f, a1 = 0.f, a2 = 0.f, a3 = 0.f, a4 = 0.f;
#pragma unroll
    for (int j = 0; j < 8; ++j) {
        const int h = lane + j * 64;
        float y = Hm[(size_t)row * HH + h] * sscale[h] + sshift[h];
        y = fmaxf(y, 0.f);
        a0 += y * w[j][0]; a1 += y * w[j][1]; a2 += y * w[j][2];
        a3 += y * w[j][3]; a4 += y * w[j][4];
    }
#pragma unroll
    for (int off = 32; off > 0; off >>= 1) {
        a0 += __shfl_down(a0, off, 64);
        a1 += __shfl_down(a1, off, 64);
        a2 += __shfl_down(a2, off, 64);
        a3 += __shfl_down(a3, off, 64);
        a4 += __shfl_down(a4, off, 64);
    }
    if (lane == 0) {
        out[row * NOUT + 0] = a0 + b2[0];
        out[row * NOUT + 1] = a1 + b2[1];
        out[row * NOUT + 2] = a2 + b2[2];
        out[row * NOUT + 3] = a3 + b2[3];
        out[row * NOUT + 4] = a4 + b2[4];
    }
}

extern "C" void kernel_launch(void* const* d_in, const int* in_sizes, int n_in,
                              void* d_out, int out_size, void* d_ws, size_t ws_size,
                              hipStream_t stream) {
    const int*   tokens  = (const int*)d_in[0];
    const int*   lengths = (const int*)d_in[1];
    const float* emb     = (const float*)d_in[2];
    const float* W1      = (const float*)d_in[3];
    const float* b1      = (const float*)d_in[4];
    const float* gamma   = (const float*)d_in[5];
    const float* beta    = (const float*)d_in[6];
    const float* W2      = (const float*)d_in[7];
    const float* b2      = (const float*)d_in[8];
    float* out = (float*)d_out;

    float* ws   = (float*)d_ws;
    float* hpre = ws;                          // 1024*512 f32
    float* ps   = hpre + BB * HH;              // 512
    float* pq   = ps + HH;                     // 512
    float* part = pq + HH;                     // 4096*512 f32 (8 MB)
    unsigned short* Apk = (unsigned short*)(part + (size_t)BB * NSUB * HH);
    unsigned short* Bpk = Apk + (size_t)BB * HH;

    pool_partial<<<BB * NSUB, 256, 0, stream>>>(tokens, lengths, emb, part);
    pack_kernel<<<768, 256, 0, stream>>>(part, lengths, W1, Apk, Bpk, ps);
    gemm1_mfma<<<dim3(HH / 64, BB / 64), 256, 0, stream>>>(Apk, Bpk, b1, hpre, ps, pq);
    bn_out_kernel<<<BB / 4, 256, 0, stream>>>(hpre, ps, pq, gamma, beta, W2, b2, out);
}